// Round 1
// baseline (8531.698 us; speedup 1.0000x reference)
//
#include <hip/hip_runtime.h>
#include <math.h>

// Problem dims (fixed by reference)
//  B=1024, T=128, I=128, H=256, 3H=768, K=8, E1=512, E2=256, C=2

// ---------------------------------------------------------------------------
// Tiled fp32 GEMM: C[m, z, n] = act( sum_k Arow(m,z)[k] * W[z][n][k] + b[z][n] )
// A row address = A + (m>>10)*a_sT + (m&1023)*a_sB + z*a_sZ   (row-of-K floats)
// M must be a multiple of 128, N of 64, K of 16.
// ---------------------------------------------------------------------------
template<int ACT>
__global__ __launch_bounds__(256)
void gemm_nt(const float* __restrict__ A, const float* __restrict__ W,
             const float* __restrict__ bias, float* __restrict__ C,
             int K,
             long a_sT, long a_sB, long a_sZ,
             long w_sZ, long b_sZ, long c_row, long c_sZ)
{
  __shared__ alignas(16) float As[16][132];
  __shared__ alignas(16) float Ws[16][68];
  const int z = blockIdx.z;
  const float* Wz = W + (long)z * w_sZ;
  const float* bz = bias + (long)z * b_sZ;
  const float* Az = A + (long)z * a_sZ;
  const int m0 = blockIdx.y * 128;
  const int n0 = blockIdx.x * 64;
  const int tid = threadIdx.x;
  const int tx = tid & 15, ty = tid >> 4;

  float acc[8][4];
  #pragma unroll
  for (int i = 0; i < 8; ++i)
    #pragma unroll
    for (int j = 0; j < 4; ++j) acc[i][j] = 0.f;

  for (int k0 = 0; k0 < K; k0 += 16) {
    #pragma unroll
    for (int p = 0; p < 2; ++p) {
      int idx = tid + p * 256;        // 0..511 -> 512 float4 = 128 rows x 16 k
      int row = idx >> 2;
      int kq  = idx & 3;
      int m = m0 + row;
      const float* ap = Az + (long)(m >> 10) * a_sT + (long)(m & 1023) * a_sB
                           + k0 + kq * 4;
      float4 v = *(const float4*)ap;
      As[kq*4+0][row] = v.x; As[kq*4+1][row] = v.y;
      As[kq*4+2][row] = v.z; As[kq*4+3][row] = v.w;
    }
    {
      int row = tid >> 2, kq = tid & 3;   // 64 rows x 16 k
      const float* wp = Wz + (long)(n0 + row) * K + k0 + kq * 4;
      float4 v = *(const float4*)wp;
      Ws[kq*4+0][row] = v.x; Ws[kq*4+1][row] = v.y;
      Ws[kq*4+2][row] = v.z; Ws[kq*4+3][row] = v.w;
    }
    __syncthreads();
    #pragma unroll
    for (int kk = 0; kk < 16; ++kk) {
      float4 a0 = *(const float4*)&As[kk][ty*8];
      float4 a1 = *(const float4*)&As[kk][ty*8+4];
      float4 wv = *(const float4*)&Ws[kk][tx*4];
      float a[8] = {a0.x,a0.y,a0.z,a0.w,a1.x,a1.y,a1.z,a1.w};
      float w[4] = {wv.x,wv.y,wv.z,wv.w};
      #pragma unroll
      for (int i = 0; i < 8; ++i)
        #pragma unroll
        for (int j = 0; j < 4; ++j)
          acc[i][j] = fmaf(a[i], w[j], acc[i][j]);
    }
    __syncthreads();
  }
  #pragma unroll
  for (int i = 0; i < 8; ++i) {
    int m = m0 + ty*8 + i;
    float* cp = C + (long)m * c_row + (long)z * c_sZ + n0 + tx*4;
    float4 o;
    o.x = acc[i][0] + bz[n0+tx*4+0];
    o.y = acc[i][1] + bz[n0+tx*4+1];
    o.z = acc[i][2] + bz[n0+tx*4+2];
    o.w = acc[i][3] + bz[n0+tx*4+3];
    if (ACT == 1) {
      o.x = fmaxf(o.x, 0.f); o.y = fmaxf(o.y, 0.f);
      o.z = fmaxf(o.z, 0.f); o.w = fmaxf(o.w, 0.f);
    }
    *(float4*)cp = o;
  }
}

// ---------------------------------------------------------------------------
// GRU recurrence over Tc steps. One block = 4 batch rows, persistent over time.
// gi: [Tc, 1024, 768] precomputed x@W_ih^T + b_ih (gate order r,z,n).
// Thread d (=tid) owns hidden dim d: computes gh rows d, 256+d, 512+d.
// h kept in LDS; W_hh streamed from L2 (cached: 786 KB).
// ---------------------------------------------------------------------------
__global__ __launch_bounds__(256)
void gru_rec(const float* __restrict__ gi, const float* __restrict__ Whh,
             const float* __restrict__ b_hh, float* __restrict__ h_state,
             float* __restrict__ h_out, int Tc, int store_all)
{
  __shared__ alignas(16) float hs[4][256];
  const int tid = threadIdx.x;
  const int b0 = blockIdx.x * 4;
  #pragma unroll
  for (int r = 0; r < 4; ++r)
    hs[r][tid] = h_state[(long)(b0 + r) * 256 + tid];
  __syncthreads();

  const float bhr = b_hh[tid];
  const float bhz = b_hh[256 + tid];
  const float bhn = b_hh[512 + tid];
  const float4* Wr = (const float4*)(Whh + (long)tid * 256);
  const float4* Wz = (const float4*)(Whh + (long)(256 + tid) * 256);
  const float4* Wn = (const float4*)(Whh + (long)(512 + tid) * 256);

  for (int t = 0; t < Tc; ++t) {
    float ar[4] = {0,0,0,0}, az[4] = {0,0,0,0}, an[4] = {0,0,0,0};
    for (int k4 = 0; k4 < 64; ++k4) {
      float4 wr = Wr[k4], wz = Wz[k4], wn = Wn[k4];
      #pragma unroll
      for (int r = 0; r < 4; ++r) {
        float4 hv = *(const float4*)&hs[r][k4 * 4];   // LDS broadcast
        ar[r] = fmaf(hv.x, wr.x, ar[r]); ar[r] = fmaf(hv.y, wr.y, ar[r]);
        ar[r] = fmaf(hv.z, wr.z, ar[r]); ar[r] = fmaf(hv.w, wr.w, ar[r]);
        az[r] = fmaf(hv.x, wz.x, az[r]); az[r] = fmaf(hv.y, wz.y, az[r]);
        az[r] = fmaf(hv.z, wz.z, az[r]); az[r] = fmaf(hv.w, wz.w, az[r]);
        an[r] = fmaf(hv.x, wn.x, an[r]); an[r] = fmaf(hv.y, wn.y, an[r]);
        an[r] = fmaf(hv.z, wn.z, an[r]); an[r] = fmaf(hv.w, wn.w, an[r]);
      }
    }
    float hnew[4];
    #pragma unroll
    for (int r = 0; r < 4; ++r) {
      const float* gip = gi + ((long)t * 1024 + b0 + r) * 768;
      float ir  = gip[tid];
      float iz  = gip[256 + tid];
      float in_ = gip[512 + tid];
      float rg = 1.f / (1.f + __expf(-(ir + ar[r] + bhr)));
      float zg = 1.f / (1.f + __expf(-(iz + az[r] + bhz)));
      float ng = tanhf(in_ + rg * (an[r] + bhn));
      hnew[r] = (1.f - zg) * ng + zg * hs[r][tid];
    }
    __syncthreads();   // all k-loops done reading hs before overwrite
    #pragma unroll
    for (int r = 0; r < 4; ++r) {
      hs[r][tid] = hnew[r];
      if (store_all)
        h_out[((long)t * 1024 + b0 + r) * 256 + tid] = hnew[r];
    }
    __syncthreads();
  }
  #pragma unroll
  for (int r = 0; r < 4; ++r)
    h_state[(long)(b0 + r) * 256 + tid] = hs[r][tid];
}

// ---------------------------------------------------------------------------
// Soft cluster assignment: q[b,k] ∝ 1/(1+||z_b - c_k||²)  (alpha=1), normalized.
// ---------------------------------------------------------------------------
__global__ __launch_bounds__(64)
void cluster_q(const float* __restrict__ zlat, const float* __restrict__ centers,
               float* __restrict__ q)
{
  __shared__ float red[64];
  __shared__ float qv[8];
  const int b = blockIdx.x;
  const int tid = threadIdx.x;
  const int k = tid >> 3, p = tid & 7;
  const float4* zp = (const float4*)(zlat + (long)b * 256 + p * 32);
  const float4* cp = (const float4*)(centers + (long)k * 256 + p * 32);
  float s = 0.f;
  #pragma unroll
  for (int i = 0; i < 8; ++i) {
    float4 zv = zp[i], cv = cp[i];
    float dx = zv.x - cv.x, dy = zv.y - cv.y;
    float dz = zv.z - cv.z, dw = zv.w - cv.w;
    s += dx*dx + dy*dy + dz*dz + dw*dw;
  }
  red[tid] = s;
  __syncthreads();
  if (tid < 8) {
    float d2 = 0.f;
    #pragma unroll
    for (int p2 = 0; p2 < 8; ++p2) d2 += red[tid * 8 + p2];
    qv[tid] = 1.f / (1.f + d2);
  }
  __syncthreads();
  if (tid < 8) {
    float ssum = 0.f;
    #pragma unroll
    for (int kk = 0; kk < 8; ++kk) ssum += qv[kk];
    q[(long)b * 8 + tid] = qv[tid] / ssum;
  }
}

// ---------------------------------------------------------------------------
// logits[b,k,c] = h2[b,k,:]·eW3[k,c,:] + eb3[k,c]; preds[b,c] = Σ_k q[b,k]*logits
// ---------------------------------------------------------------------------
__global__ __launch_bounds__(256)
void combine_preds(const float* __restrict__ h2, const float* __restrict__ eW3,
                   const float* __restrict__ eb3, const float* __restrict__ q,
                   float* __restrict__ out)
{
  __shared__ float p0[256], p1[256];
  __shared__ float lc[16];
  const int b = blockIdx.x;
  const int tid = threadIdx.x;
  const int k = tid >> 5, w = tid & 31;
  const float* h2p = h2 + (long)b * (8 * 256) + (long)k * 256 + w * 8;
  const float* w0  = eW3 + (long)k * 512 + w * 8;          // c=0
  const float* w1  = eW3 + (long)k * 512 + 256 + w * 8;    // c=1
  float c0 = 0.f, c1 = 0.f;
  #pragma unroll
  for (int i = 0; i < 8; ++i) {
    float hv = h2p[i];
    c0 = fmaf(hv, w0[i], c0);
    c1 = fmaf(hv, w1[i], c1);
  }
  p0[tid] = c0; p1[tid] = c1;
  __syncthreads();
  if (tid < 16) {
    int kk = tid >> 1, c = tid & 1;
    const float* pp = (c == 0) ? p0 : p1;
    float s = 0.f;
    for (int w2 = 0; w2 < 32; ++w2) s += pp[kk * 32 + w2];
    s += eb3[kk * 2 + c];
    lc[tid] = q[(long)b * 8 + kk] * s;
  }
  __syncthreads();
  if (tid < 2) {
    float s = 0.f;
    #pragma unroll
    for (int kk = 0; kk < 8; ++kk) s += lc[kk * 2 + tid];
    out[(long)b * 2 + tid] = s;
  }
}

// Zero-fill helper (avoid relying on memset semantics under graph capture)
__global__ __launch_bounds__(256)
void zero_fill(float* __restrict__ p, long n)
{
  long i = (long)blockIdx.x * 256 + threadIdx.x;
  if (i < n) p[i] = 0.f;
}

// ---------------------------------------------------------------------------
extern "C" void kernel_launch(void* const* d_in, const int* in_sizes, int n_in,
                              void* d_out, int out_size, void* d_ws, size_t ws_size,
                              hipStream_t stream)
{
  const float* x       = (const float*)d_in[0];
  const float* W_ih0   = (const float*)d_in[1];
  const float* W_hh0   = (const float*)d_in[2];
  const float* b_ih0   = (const float*)d_in[3];
  const float* b_hh0   = (const float*)d_in[4];
  const float* W_ih1   = (const float*)d_in[5];
  const float* W_hh1   = (const float*)d_in[6];
  const float* b_ih1   = (const float*)d_in[7];
  const float* b_hh1   = (const float*)d_in[8];
  const float* centers = (const float*)d_in[9];
  const float* eW1     = (const float*)d_in[10];
  const float* eb1     = (const float*)d_in[11];
  const float* eW2     = (const float*)d_in[12];
  const float* eb2     = (const float*)d_in[13];
  const float* eW3     = (const float*)d_in[14];
  const float* eb3     = (const float*)d_in[15];
  float* out = (float*)d_out;
  (void)in_sizes; (void)n_in; (void)out_size;

  // ---- workspace layout ----
  char* base = (char*)d_ws;
  size_t off = 0;
  auto alloc = [&](size_t nbytes) -> void* {
    void* p = base + off;
    off += (nbytes + 255) & ~(size_t)255;
    return p;
  };
  float* h0_state = (float*)alloc(1024ull * 256 * 4);
  float* h1_state = (float*)alloc(1024ull * 256 * 4);   // == z after layer 1
  float* qbuf     = (float*)alloc(1024ull * 8 * 4);
  float* h1buf    = (float*)alloc(1024ull * 8 * 512 * 4);
  float* h2buf    = (float*)alloc(1024ull * 8 * 256 * 4);
  const size_t fixed = off;

  // largest T-chunk that fits ws_size (deterministic given ws_size)
  int Tc = 1;
  const int cands[7] = {128, 64, 32, 16, 8, 4, 2};
  for (int ci = 0; ci < 7; ++ci) {
    size_t need = fixed + (size_t)cands[ci] * 1024 * (768 + 768 + 256) * 4 + 1024;
    if (need <= ws_size) { Tc = cands[ci]; break; }
  }
  float* gi0 = (float*)alloc((size_t)Tc * 1024 * 768 * 4);
  float* gi1 = (float*)alloc((size_t)Tc * 1024 * 768 * 4);
  float* h0c = (float*)alloc((size_t)Tc * 1024 * 256 * 4);

  // ---- zero recurrent states (ws is poisoned 0xAA before every call) ----
  {
    long n = 2L * 1024 * 256;   // h0_state + h1_state are contiguous
    zero_fill<<<dim3((unsigned)((n + 255) / 256)), 256, 0, stream>>>(h0_state, n);
  }

  // ---- 2-layer GRU, chunked over time ----
  for (int t0 = 0; t0 < 128; t0 += Tc) {
    // gi0[tl,b,:] = x[b, t0+tl, :] @ W_ih0^T + b_ih0
    gemm_nt<0><<<dim3(12, Tc * 8, 1), 256, 0, stream>>>(
        x + (long)t0 * 128, W_ih0, b_ih0, gi0, 128,
        /*a_sT*/ 128, /*a_sB*/ 128L * 128, /*a_sZ*/ 0,
        /*w_sZ*/ 0, /*b_sZ*/ 0, /*c_row*/ 768, /*c_sZ*/ 0);
    gru_rec<<<256, 256, 0, stream>>>(gi0, W_hh0, b_hh0, h0_state, h0c, Tc, 1);

    // gi1[tl,b,:] = h0c[tl,b,:] @ W_ih1^T + b_ih1
    gemm_nt<0><<<dim3(12, Tc * 8, 1), 256, 0, stream>>>(
        h0c, W_ih1, b_ih1, gi1, 256,
        /*a_sT*/ 1024L * 256, /*a_sB*/ 256, /*a_sZ*/ 0,
        /*w_sZ*/ 0, /*b_sZ*/ 0, /*c_row*/ 768, /*c_sZ*/ 0);
    gru_rec<<<256, 256, 0, stream>>>(gi1, W_hh1, b_hh1, h1_state, nullptr, Tc, 0);
  }

  // ---- soft cluster assignment ----
  cluster_q<<<1024, 64, 0, stream>>>(h1_state, centers, qbuf);

  // ---- experts: h1 = relu(z @ eW1[k]^T + eb1[k]) ----
  gemm_nt<1><<<dim3(8, 8, 8), 256, 0, stream>>>(
      h1_state, eW1, eb1, h1buf, 256,
      /*a_sT*/ 0, /*a_sB*/ 256, /*a_sZ*/ 0,
      /*w_sZ*/ 512L * 256, /*b_sZ*/ 512, /*c_row*/ 8L * 512, /*c_sZ*/ 512);
  // h2 = relu(h1 @ eW2[k]^T + eb2[k])
  gemm_nt<1><<<dim3(4, 8, 8), 256, 0, stream>>>(
      h1buf, eW2, eb2, h2buf, 512,
      /*a_sT*/ 0, /*a_sB*/ 8L * 512, /*a_sZ*/ 512,
      /*w_sZ*/ 256L * 512, /*b_sZ*/ 256, /*c_row*/ 8L * 256, /*c_sZ*/ 256);

  // ---- logits + q-weighted combine ----
  combine_preds<<<1024, 256, 0, stream>>>(h2buf, eW3, eb3, qbuf, out);
}